// Round 7
// baseline (592.899 us; speedup 1.0000x reference)
//
#include <hip/hip_runtime.h>
#include <hip/hip_bf16.h>
#include <stdint.h>

typedef __bf16 bf16;
typedef bf16 bf16x8 __attribute__((ext_vector_type(8)));
typedef bf16 bf16x4 __attribute__((ext_vector_type(4)));
typedef float floatx4 __attribute__((ext_vector_type(4)));

#define DM   4096
#define NSEQ 2048
#define NH   32
#define DH   128
#define NQB  16   // 2048 / 128 query blocks

// Q pre-scale folded into the fused Q-GEMM epilogue: 1/sqrt(128) * log2(e)
#define QSCALE 0.12753102494739462f

// ---------- helpers ----------

__device__ __forceinline__ bf16 cvt_bf16(float f) {
  uint32_t u = __builtin_bit_cast(uint32_t, f);
  u += 0x7FFFu + ((u >> 16) & 1u);          // RTNE
  uint16_t h = (uint16_t)(u >> 16);
  return __builtin_bit_cast(bf16, h);
}

// pack 2 fp32 -> 2 bf16 (round-half-up) in 3 VALU: add, add, v_perm
__device__ __forceinline__ uint32_t pack_bf16_2(float f0, float f1) {
  uint32_t u0 = __builtin_bit_cast(uint32_t, f0) + 0x8000u;
  uint32_t u1 = __builtin_bit_cast(uint32_t, f1) + 0x8000u;
  return __builtin_amdgcn_perm(u1, u0, 0x07060302);   // [u1.hi16 | u0.hi16]
}

// async global->LDS, 16B per lane. LDS dest is wave-uniform base + lane*16.
__device__ __forceinline__ void gload_lds16(const bf16* g, bf16* l) {
  __builtin_amdgcn_global_load_lds(
      (__attribute__((address_space(1))) uint32_t*)(uintptr_t)g,
      (__attribute__((address_space(3))) uint32_t*)l,
      16, 0, 0);
}

// ---------- fused prep: KV projection + x cast + Wq (+Wo) transpose-cast ----------
// Block ranges (uniform branch per block):
//   [0, 128)        : KV projection GEMM (reads RAW f32 x/Wk/Wv; latency-bound,
//                     hidden under the memory-bound streams). Block 0 also
//                     zeroes cnt[16] (re-zeroed every graph replay; attn_out's
//                     spin counters must start at 0 each launch).
//   [128, 8320)     : cast x (4 f32 -> bf16 per thread)
//   [8320, 12416)   : transpose Wq
//   [12416, 16512)  : transpose Wo into dedicated WoT (bigws path only)

__global__ __launch_bounds__(256)
void prep_all(const float* __restrict__ x,  const float* __restrict__ Wq,
              const float* __restrict__ Wk, const float* __restrict__ Wv,
              const float* __restrict__ bk, const float* __restrict__ bv,
              bf16* __restrict__ xb, bf16* __restrict__ WqT,
              bf16* __restrict__ Kb, bf16* __restrict__ Vt,
              const float* __restrict__ Wo, bf16* __restrict__ WoT,
              uint32_t* __restrict__ cnt)
{
  __shared__ __align__(16) bf16 smem[2 * 64 * 64];   // 16KB: KV As+Bs, or transpose tile
  int id = blockIdx.x;
  const int tid = threadIdx.x;

  if (id < 128) {                        // ---- KV projection ----
    if (id == 0 && tid < NQB) cnt[tid] = 0;           // reset spin counters
    const int m0 = (id >> 2) * 64;
    const int n0 = (id & 3) * 64;                     // 0,64 -> K; 128,192 -> V
    const float* __restrict__ W    = (n0 < 128) ? Wk : Wv;
    const float* __restrict__ bias = (n0 < 128) ? bk : bv;
    const int nc0 = n0 & 127;
    bf16* As = smem;                                  // [64][64] XOR-chunk swizzled
    bf16* Bs = smem + 64 * 64;

    float a[16], bw[16];
    auto loadA = [&](int k0) {
      const float4* p = (const float4*)&x[(size_t)(m0 + (tid >> 2)) * DM + k0 + (tid & 3) * 16];
      *(float4*)&a[0] = p[0]; *(float4*)&a[4]  = p[1];
      *(float4*)&a[8] = p[2]; *(float4*)&a[12] = p[3];
    };
    auto loadB = [&](int k0) {
      #pragma unroll
      for (int j = 0; j < 16; ++j)
        bw[j] = W[(size_t)(k0 + (tid >> 6) * 16 + j) * DH + nc0 + (tid & 63)];
    };
    auto store = [&]() {
      int r = tid >> 2, ca = (tid & 3) * 2;
      bf16x8 v0, v1;
      #pragma unroll
      for (int j = 0; j < 8; ++j) { v0[j] = cvt_bf16(a[j]); v1[j] = cvt_bf16(a[8 + j]); }
      *(bf16x8*)&As[r * 64 + ((ca       ^ (r & 7)) * 8)] = v0;
      *(bf16x8*)&As[r * 64 + (((ca + 1) ^ (r & 7)) * 8)] = v1;
      int n = tid & 63, cb = (tid >> 6) * 2;
      bf16x8 w0, w1;
      #pragma unroll
      for (int j = 0; j < 8; ++j) { w0[j] = cvt_bf16(bw[j]); w1[j] = cvt_bf16(bw[8 + j]); }
      *(bf16x8*)&Bs[n * 64 + ((cb       ^ (n & 7)) * 8)] = w0;
      *(bf16x8*)&Bs[n * 64 + (((cb + 1) ^ (n & 7)) * 8)] = w1;
    };

    const int lane = tid & 63, wave = tid >> 6;
    const int quad = lane >> 4, l15 = lane & 15;
    const int wm = wave >> 1, wn = wave & 1;
    floatx4 acc[2][2] = {};

    loadA(0); loadB(0);
    for (int k0 = 0; k0 < DM; k0 += 64) {
      store();
      __syncthreads();
      if (k0 + 64 < DM) { loadA(k0 + 64); loadB(k0 + 64); }
      #pragma unroll
      for (int kk = 0; kk < 2; ++kk) {
        bf16x8 af[2], bfr[2];
        #pragma unroll
        for (int mt = 0; mt < 2; ++mt) {
          int r = wm * 32 + mt * 16 + l15;
          af[mt] = *(const bf16x8*)&As[r * 64 + (((kk * 4 + quad) ^ (r & 7)) * 8)];
        }
        #pragma unroll
        for (int nt = 0; nt < 2; ++nt) {
          int r = wn * 32 + nt * 16 + l15;
          bfr[nt] = *(const bf16x8*)&Bs[r * 64 + (((kk * 4 + quad) ^ (r & 7)) * 8)];
        }
        #pragma unroll
        for (int mt = 0; mt < 2; ++mt)
          #pragma unroll
          for (int nt = 0; nt < 2; ++nt)
            acc[mt][nt] = __builtin_amdgcn_mfma_f32_16x16x32_bf16(af[mt], bfr[nt], acc[mt][nt], 0, 0, 0);
      }
      __syncthreads();
    }

    #pragma unroll
    for (int mt = 0; mt < 2; ++mt)
      #pragma unroll
      for (int nt = 0; nt < 2; ++nt) {
        int cl = wn * 32 + nt * 16 + l15;
        #pragma unroll
        for (int r = 0; r < 4; ++r) {
          int row = m0 + wm * 32 + mt * 16 + quad * 4 + r;
          float v = acc[mt][nt][r] + bias[nc0 + cl];
          if (n0 < 128) Kb[(size_t)row * DH + nc0 + cl]      = cvt_bf16(v);
          else          Vt[(size_t)(nc0 + cl) * NSEQ + row]  = cvt_bf16(v);
        }
      }
    return;
  }
  id -= 128;

  if (id < 8192) {                       // ---- cast x ----
    int i = (id * 256 + tid) * 4;
    float4 v = *(const float4*)&x[i];
    bf16x4 o;
    o[0] = cvt_bf16(v.x); o[1] = cvt_bf16(v.y);
    o[2] = cvt_bf16(v.z); o[3] = cvt_bf16(v.w);
    *(bf16x4*)&xb[i] = o;
    return;
  }
  id -= 8192;

  // ---- transpose Wq (ids < 4096) or Wo (ids >= 4096) : 64x64 tile ----
  const float* in; bf16* out;
  if (id < 4096) { in = Wq; out = WqT; }
  else           { id -= 4096; in = Wo; out = WoT; }
  bf16 (*t)[72] = (bf16(*)[72])&smem[0];
  int bx = id & 63, by = id >> 6;
  int tx = tid & 15, ty = tid >> 4;
  int r0 = by * 64, c0 = bx * 64;
  #pragma unroll
  for (int i = 0; i < 4; ++i) {
    float4 v = *(const float4*)&in[(size_t)(r0 + ty + i * 16) * DM + c0 + tx * 4];
    bf16x4 b;
    b[0] = cvt_bf16(v.x); b[1] = cvt_bf16(v.y);
    b[2] = cvt_bf16(v.z); b[3] = cvt_bf16(v.w);
    *(bf16x4*)&t[ty + i * 16][tx * 4] = b;
  }
  __syncthreads();
  #pragma unroll
  for (int i = 0; i < 4; ++i) {
    int cc = ty + i * 16;
    bf16x4 o;
    #pragma unroll
    for (int j = 0; j < 4; ++j) o[j] = t[tx * 4 + j][cc];
    *(bf16x4*)&out[(size_t)(c0 + cc) * DM + r0 + tx * 4] = o;
  }
}

// ---------- standalone Wo transpose (small-ws fallback only) ----------

__global__ void wo_t(const float* __restrict__ in, bf16* __restrict__ out) {
  __shared__ bf16 t[64][72];
  int tx = threadIdx.x & 15, ty = threadIdx.x >> 4;
  int r0 = blockIdx.y * 64, c0 = blockIdx.x * 64;
  #pragma unroll
  for (int i = 0; i < 4; ++i) {
    float4 v = *(const float4*)&in[(size_t)(r0 + ty + i * 16) * DM + c0 + tx * 4];
    bf16x4 b;
    b[0] = cvt_bf16(v.x); b[1] = cvt_bf16(v.y);
    b[2] = cvt_bf16(v.z); b[3] = cvt_bf16(v.w);
    *(bf16x4*)&t[ty + i * 16][tx * 4] = b;
  }
  __syncthreads();
  #pragma unroll
  for (int i = 0; i < 4; ++i) {
    int cc = ty + i * 16;
    bf16x4 o;
    #pragma unroll
    for (int j = 0; j < 4; ++j) o[j] = t[tx * 4 + j][cc];
    *(bf16x4*)&out[(size_t)(c0 + cc) * DM + r0 + tx * 4] = o;
  }
}

// ---------- NT GEMM core: C[M,N] = A[M,K] * B[N,K]^T + bias ----------
// m97 recipe, 16x16x32 MFMA, single-barrier double-buffered gload_lds staging.
// MODE 0: f32 out + bias (global)
// MODE 2: bf16 out to LDS tile outb[128][128], (v+bias[col])*QSCALE

template<int BM, int BN, int MODE>
__device__ __forceinline__ void gemm_core(
    const bf16* __restrict__ A, const bf16* __restrict__ B,
    const float* __restrict__ bias,
    float* __restrict__ outf, bf16* __restrict__ outb,
    int N, int K, int m0, int n0,
    bf16* __restrict__ As, bf16* __restrict__ Bs)
{
  constexpr int BK = 64;
  constexpr int TM = BM / 2, TN = BN / 2;
  constexpr int MT = TM / 16, NT = TN / 16;
  const int tid  = threadIdx.x;
  const int lane = tid & 63;
  const int wave = tid >> 6;
  const int quad = lane >> 4;
  const int l15  = lane & 15;
  const int wm = wave >> 1, wn = wave & 1;

  auto stage = [&](int k0, int buf) {
    #pragma unroll
    for (int i = 0; i < BM / 32; ++i) {
      int c = i * 256 + tid;
      int r = c >> 3, kc = (c & 7) ^ (r & 7);          // 8-chunk XOR swizzle
      gload_lds16(A + (size_t)(m0 + r) * K + k0 + kc * 8, &As[buf * BM * BK + c * 8]);
    }
    #pragma unroll
    for (int i = 0; i < BN / 32; ++i) {
      int c = i * 256 + tid;
      int r = c >> 3, kc = (c & 7) ^ (r & 7);
      gload_lds16(B + (size_t)(n0 + r) * K + k0 + kc * 8, &Bs[buf * BN * BK + c * 8]);
    }
  };

  floatx4 acc[MT][NT] = {};
  stage(0, 0);

  int b = 0;
  for (int k0 = 0; k0 < K; k0 += BK, b ^= 1) {
    __syncthreads();                                    // drains staging of buf b
    if (k0 + BK < K) stage(k0 + BK, b ^ 1);             // overlaps compute below

    #pragma unroll
    for (int kk = 0; kk < 2; ++kk) {
      bf16x8 af[MT], bfr[NT];
      #pragma unroll
      for (int mt = 0; mt < MT; ++mt) {
        int r = wm * TM + mt * 16 + l15;
        af[mt] = *(const bf16x8*)&As[b * BM * BK + r * BK + (((kk * 4 + quad) ^ (r & 7)) * 8)];
      }
      #pragma unroll
      for (int nt = 0; nt < NT; ++nt) {
        int r = wn * TN + nt * 16 + l15;
        bfr[nt] = *(const bf16x8*)&Bs[b * BN * BK + r * BK + (((kk * 4 + quad) ^ (r & 7)) * 8)];
      }
      #pragma unroll
      for (int mt = 0; mt < MT; ++mt)
        #pragma unroll
        for (int nt = 0; nt < NT; ++nt)
          acc[mt][nt] = __builtin_amdgcn_mfma_f32_16x16x32_bf16(af[mt], bfr[nt], acc[mt][nt], 0, 0, 0);
    }
  }

  if constexpr (MODE == 2) __syncthreads();             // outb aliases As

  #pragma unroll
  for (int mt = 0; mt < MT; ++mt) {
    #pragma unroll
    for (int nt = 0; nt < NT; ++nt) {
      int col = n0 + wn * TN + nt * 16 + l15;
      #pragma unroll
      for (int r = 0; r < 4; ++r) {
        int row = m0 + wm * TM + mt * 16 + quad * 4 + r;
        float v = acc[mt][nt][r];
        if constexpr (MODE == 0) {
          outf[(size_t)row * N + col] = v + bias[col];
        } else {  // MODE 2: LDS Q tile
          int rl = wm * TM + mt * 16 + quad * 4 + r;
          int cl = wn * TN + nt * 16 + l15;
          outb[rl * 128 + cl] = cvt_bf16((v + bias[col]) * QSCALE);
        }
      }
    }
  }
}

// ---------- fused Q-GEMM + flash attention + O-projection (one plain launch) ----------
// MODE 0 (fused): block (qb,h) runs {Q-tile GEMM -> flash attention -> release
//   cnt[qb] -> spin until cnt[qb]==NH -> O-tile (m=qb*128, n=h*128)}.
//   Deadlock-free WITHOUT co-residency: spins only occur after a block's own
//   producible work, so any resident subset makes progress (round-6 lesson:
//   hipLaunchCooperativeKernel silently rejected 512x80KB; this needs no coop).
//   cnt zeroed by prep_all each launch (stream-ordered -> fresh every replay).
// MODE 1 / MODE 2: flash-only / O-only (small-ws fallback path).

struct GemmSm { bf16 As[2 * 128 * 64]; bf16 Bs[2 * 128 * 64]; };
struct AttnSm { bf16 Ks[2][64 * DH]; bf16 Vs[2][DH * 64]; bf16 Pl[4][32 * 64]; };
union FlashSm { GemmSm g; AttnSm a; bf16 Qt[128 * 128]; };

template<int MODE>
__global__ __launch_bounds__(256)
void attn_out(const bf16* __restrict__ xb, const bf16* __restrict__ WqT,
              const float* __restrict__ bq,
              const bf16* __restrict__ Kb, const bf16* __restrict__ Vt,
              bf16* __restrict__ Ob, const bf16* __restrict__ WoT,
              const float* __restrict__ bo, float* __restrict__ out,
              uint32_t* __restrict__ cnt)
{
  constexpr int KT = 64;
  __shared__ __align__(16) FlashSm sm;
  const int tid = threadIdx.x, lane = tid & 63, wave = tid >> 6;
  const int quad = lane >> 4, l15 = lane & 15;
  const int id  = blockIdx.x;
  const int per = 4 * (DM / 128);                 // 128 (group-of-4 m swizzle)
  const int qb  = (id / per) * 4 + (id % per) % 4;
  const int h   = (id % per) / 4;

  if constexpr (MODE != 2) {
    // ---- phase 1: Q tile = xb[qb*128..][:] @ WqT[h*128..][:]^T ----
    gemm_core<128, 128, 2>(xb, WqT, bq, nullptr, sm.Qt, DM, DM,
                           qb * 128, h * 128, sm.g.As, sm.g.Bs);
    __syncthreads();                              // Qt complete

    bf16x8 qf[2][4];
    #pragma unroll
    for (int mt = 0; mt < 2; ++mt)
      #pragma unroll
      for (int kf = 0; kf < 4; ++kf)
        qf[mt][kf] = *(const bf16x8*)&sm.Qt[(wave * 32 + mt * 16 + l15) * 128 + kf * 32 + quad * 8];
    __syncthreads();                              // qf read before Ks overwrites Qt

    const int q0 = qb * 128 + wave * 32;

    auto stage = [&](int kt, int buf) {
      #pragma unroll
      for (int i = 0; i < 4; ++i) {                // K tile (64 x 128)
        int c = i * 256 + tid, n = c >> 4, kc = (c & 15) ^ (n & 15);
        gload_lds16(Kb + (size_t)(kt + n) * DH + kc * 8, &sm.a.Ks[buf][c * 8]);
      }
      #pragma unroll
      for (int i = 0; i < 4; ++i) {                // V tile (128 x 64)
        int c = i * 256 + tid, n = c >> 3, kc = (c & 7) ^ (n & 7);
        gload_lds16(Vt + (size_t)n * NSEQ + kt + kc * 8, &sm.a.Vs[buf][c * 8]);
      }
    };

    floatx4 o[2][8] = {};
    float lsum[2] = {0.f, 0.f};
    stage(0, 0);

    int b = 0;
    for (int kt = 0; kt < NSEQ; kt += KT, b ^= 1) {
      __syncthreads();                             // drains staging of buf b
      if (kt + KT < NSEQ) stage(kt + KT, b ^ 1);   // overlaps compute below

      // St = K Q^T
      #pragma unroll
      for (int nt = 0; nt < 4; ++nt) {
        bf16x8 kfr[4];
        #pragma unroll
        for (int kf = 0; kf < 4; ++kf) {
          int r = nt * 16 + l15;
          kfr[kf] = *(const bf16x8*)&sm.a.Ks[b][r * DH + (((kf * 4 + quad) ^ (r & 15)) * 8)];
        }
        floatx4 s[2] = {};
        __builtin_amdgcn_s_setprio(1);
        #pragma unroll
        for (int kf = 0; kf < 4; ++kf)
          #pragma unroll
          for (int mt = 0; mt < 2; ++mt)
            s[mt] = __builtin_amdgcn_mfma_f32_16x16x32_bf16(kfr[kf], qf[mt][kf], s[mt], 0, 0, 0);
        __builtin_amdgcn_s_setprio(0);
        // p = exp2(s); in-lane l accumulation; packed b64 P write
        #pragma unroll
        for (int mt = 0; mt < 2; ++mt) {
          float p0 = __builtin_amdgcn_exp2f(s[mt][0]);
          float p1 = __builtin_amdgcn_exp2f(s[mt][1]);
          float p2 = __builtin_amdgcn_exp2f(s[mt][2]);
          float p3 = __builtin_amdgcn_exp2f(s[mt][3]);
          lsum[mt] += (p0 + p1) + (p2 + p3);
          uint2 pk;
          pk.x = pack_bf16_2(p0, p1);
          pk.y = pack_bf16_2(p2, p3);
          int row = mt * 16 + l15;
          int cp  = (nt * 2 + (quad >> 1)) ^ (row & 7);    // 8-chunk XOR swizzle
          *(uint2*)&sm.a.Pl[wave][row * KT + cp * 8 + (quad & 1) * 4] = pk;
        }
      }

      // O += P V
      #pragma unroll
      for (int kf = 0; kf < 2; ++kf) {
        bf16x8 pf[2];
        #pragma unroll
        for (int mt = 0; mt < 2; ++mt) {
          int row = mt * 16 + l15;
          pf[mt] = *(const bf16x8*)&sm.a.Pl[wave][row * KT + (((kf * 4 + quad) ^ (row & 7)) * 8)];
        }
        __builtin_amdgcn_s_setprio(1);
        #pragma unroll
        for (int dt = 0; dt < 8; ++dt) {
          int r = dt * 16 + l15;
          bf16x8 vf = *(const bf16x8*)&sm.a.Vs[b][r * KT + (((kf * 4 + quad) ^ (r & 7)) * 8)];
          #pragma unroll
          for (int mt = 0; mt < 2; ++mt)
            o[mt][dt] = __builtin_amdgcn_mfma_f32_16x16x32_bf16(pf[mt], vf, o[mt][dt], 0, 0, 0);
        }
        __builtin_amdgcn_s_setprio(0);
      }
    }

    // final l reduction across quads, then Ob epilogue
    #pragma unroll
    for (int mt = 0; mt < 2; ++mt) {
      lsum[mt] += __shfl_xor(lsum[mt], 16, 64);
      lsum[mt] += __shfl_xor(lsum[mt], 32, 64);
    }

    #pragma unroll
    for (int mt = 0; mt < 2; ++mt) {
      float inv[4];
      #pragma unroll
      for (int r = 0; r < 4; ++r)
        inv[r] = 1.0f / __shfl(lsum[mt], quad * 4 + r, 64);
      #pragma unroll
      for (int dt = 0; dt < 8; ++dt) {
        int col = h * DH + dt * 16 + l15;
        #pragma unroll
        for (int r = 0; r < 4; ++r) {
          int row = q0 + mt * 16 + quad * 4 + r;
          Ob[(size_t)row * DM + col] = cvt_bf16(o[mt][dt][r] * inv[r]);
        }
      }
    }
  }

  if constexpr (MODE == 0) {
    // release: Ob tile visible device-wide, then bump this qb's counter
    __threadfence();
    __syncthreads();                               // all waves' Ob stores fenced
    if (tid == 0)
      __hip_atomic_fetch_add(&cnt[qb], 1u, __ATOMIC_RELEASE, __HIP_MEMORY_SCOPE_AGENT);
    // acquire: wait for all 32 heads of this qb row-block
    if (tid == 0) {
      while (__hip_atomic_load(&cnt[qb], __ATOMIC_ACQUIRE, __HIP_MEMORY_SCOPE_AGENT) < NH)
        __builtin_amdgcn_s_sleep(8);
    }
    __syncthreads();
    __threadfence();                               // L1/L2 inv for all waves
  }

  if constexpr (MODE != 1) {
    // ---- phase 2: O tile = Ob[qb*128..][:] @ WoT[h*128..][:]^T ----
    gemm_core<128, 128, 0>(Ob, WoT, bo, out, nullptr, DM, DM,
                           qb * 128, h * 128, sm.g.As, sm.g.Bs);
  }
}

// ---------- launch ----------

extern "C" void kernel_launch(void* const* d_in, const int* in_sizes, int n_in,
                              void* d_out, int out_size, void* d_ws, size_t ws_size,
                              hipStream_t stream) {
  (void)in_sizes; (void)n_in; (void)out_size;
  const float* x  = (const float*)d_in[0];
  const float* Wq = (const float*)d_in[1];
  const float* bq = (const float*)d_in[2];
  const float* Wk = (const float*)d_in[3];
  const float* bk = (const float*)d_in[4];
  const float* Wv = (const float*)d_in[5];
  const float* bv = (const float*)d_in[6];
  const float* Wo = (const float*)d_in[7];
  const float* bo = (const float*)d_in[8];
  float* out = (float*)d_out;

  char* ws = (char*)d_ws;
  size_t off = 0;
  auto alloc = [&](size_t bytes) {
    char* p = ws + off;
    off += (bytes + 255) & ~(size_t)255;
    return p;
  };
  bf16*     xb  = (bf16*)alloc((size_t)NSEQ * DM * 2);   // x bf16
  bf16*     WT  = (bf16*)alloc((size_t)DM * DM * 2);     // WqT (and WoT in fallback)
  bf16*     Ob  = (bf16*)alloc((size_t)NSEQ * DM * 2);   // attention output
  bf16*     Kb  = (bf16*)alloc((size_t)NSEQ * DH * 2);
  bf16*     Vt  = (bf16*)alloc((size_t)DH * NSEQ * 2);
  uint32_t* cnt = (uint32_t*)alloc(NQB * 4);             // per-qb completion counters
  size_t base_off = off;
  bf16* WoTbuf = (bf16*)alloc((size_t)DM * DM * 2);      // dedicated WoT (big-ws path)
  if (base_off > ws_size) return;                        // cannot run at all
  const bool bigws = (off <= ws_size);
  bf16* WoT = bigws ? WoTbuf : WT;

  // 1) prep: KV projection + cnt reset + x cast + Wq transpose (+ Wo if bigws)
  prep_all<<<bigws ? 16512 : 12416, 256, 0, stream>>>(
      x, Wq, Wk, Wv, bk, bv, xb, WT, Kb, Vt, Wo, bigws ? WoTbuf : nullptr, cnt);

  if (bigws) {
    // 2) single plain launch: Q-GEMM + attention + counter handoff + O-projection
    attn_out<0><<<512, 256, 0, stream>>>(xb, WT, bq, Kb, Vt, Ob, WoT, bo, out, cnt);
  } else {
    // fallback: proven round-5 3-launch path
    attn_out<1><<<512, 256, 0, stream>>>(xb, WT, bq, Kb, Vt, Ob, WoT, bo, out, cnt);
    wo_t<<<dim3(DM / 64, DM / 64), 256, 0, stream>>>(Wo, WT);
    attn_out<2><<<512, 256, 0, stream>>>(xb, WT, bq, Kb, Vt, Ob, WoT, bo, out, cnt);
  }
}

// Round 8
// 432.850 us; speedup vs baseline: 1.3698x; 1.3698x over previous
//
#include <hip/hip_runtime.h>
#include <hip/hip_bf16.h>
#include <stdint.h>

typedef __bf16 bf16;
typedef bf16 bf16x8 __attribute__((ext_vector_type(8)));
typedef bf16 bf16x4 __attribute__((ext_vector_type(4)));
typedef float floatx4 __attribute__((ext_vector_type(4)));

#define DM   4096
#define NSEQ 2048
#define NH   32
#define DH   128

// Q pre-scale folded into the fused Q-GEMM epilogue: 1/sqrt(128) * log2(e)
#define QSCALE 0.12753102494739462f

// ---------- helpers ----------

__device__ __forceinline__ bf16 cvt_bf16(float f) {
  uint32_t u = __builtin_bit_cast(uint32_t, f);
  u += 0x7FFFu + ((u >> 16) & 1u);          // RTNE
  uint16_t h = (uint16_t)(u >> 16);
  return __builtin_bit_cast(bf16, h);
}

// pack 2 fp32 -> 2 bf16 (round-half-up) in 3 VALU: add, add, v_perm
__device__ __forceinline__ uint32_t pack_bf16_2(float f0, float f1) {
  uint32_t u0 = __builtin_bit_cast(uint32_t, f0) + 0x8000u;
  uint32_t u1 = __builtin_bit_cast(uint32_t, f1) + 0x8000u;
  return __builtin_amdgcn_perm(u1, u0, 0x07060302);   // [u1.hi16 | u0.hi16]
}

// async global->LDS, 16B per lane. LDS dest is wave-uniform base + lane*16.
__device__ __forceinline__ void gload_lds16(const bf16* g, bf16* l) {
  __builtin_amdgcn_global_load_lds(
      (__attribute__((address_space(1))) uint32_t*)(uintptr_t)g,
      (__attribute__((address_space(3))) uint32_t*)l,
      16, 0, 0);
}

// ---------- fused prep: KV projection + x cast + Wq (+Wo) transpose-cast ----------
// Block ranges (uniform branch per block):
//   [0, 128)        : KV projection GEMM (reads RAW f32 x/Wk/Wv; latency-bound,
//                     fully hidden under the memory-bound streaming blocks)
//   [128, 8320)     : cast x (4 f32 -> bf16 per thread)
//   [8320, 12416)   : transpose Wq into WqT
//   [12416, 16512)  : transpose Wo into dedicated WoT (bigws path only —
//                     R7-verified; runs at full occupancy, unlike the R4
//                     mistake of packing it into an 80KB-LDS kernel)

__global__ __launch_bounds__(256)
void prep_all(const float* __restrict__ x,  const float* __restrict__ Wq,
              const float* __restrict__ Wk, const float* __restrict__ Wv,
              const float* __restrict__ bk, const float* __restrict__ bv,
              bf16* __restrict__ xb, bf16* __restrict__ WqT,
              bf16* __restrict__ Kb, bf16* __restrict__ Vt,
              const float* __restrict__ Wo, bf16* __restrict__ WoT)
{
  __shared__ __align__(16) bf16 smem[2 * 64 * 64];   // 16KB: KV As+Bs, or transpose tile
  int id = blockIdx.x;
  const int tid = threadIdx.x;

  if (id < 128) {                        // ---- KV projection ----
    const int m0 = (id >> 2) * 64;
    const int n0 = (id & 3) * 64;                     // 0,64 -> K; 128,192 -> V
    const float* __restrict__ W    = (n0 < 128) ? Wk : Wv;
    const float* __restrict__ bias = (n0 < 128) ? bk : bv;
    const int nc0 = n0 & 127;
    bf16* As = smem;                                  // [64][64] XOR-chunk swizzled
    bf16* Bs = smem + 64 * 64;

    float a[16], bw[16];
    auto loadA = [&](int k0) {
      const float4* p = (const float4*)&x[(size_t)(m0 + (tid >> 2)) * DM + k0 + (tid & 3) * 16];
      *(float4*)&a[0] = p[0]; *(float4*)&a[4]  = p[1];
      *(float4*)&a[8] = p[2]; *(float4*)&a[12] = p[3];
    };
    auto loadB = [&](int k0) {
      #pragma unroll
      for (int j = 0; j < 16; ++j)
        bw[j] = W[(size_t)(k0 + (tid >> 6) * 16 + j) * DH + nc0 + (tid & 63)];
    };
    auto store = [&]() {
      int r = tid >> 2, ca = (tid & 3) * 2;
      bf16x8 v0, v1;
      #pragma unroll
      for (int j = 0; j < 8; ++j) { v0[j] = cvt_bf16(a[j]); v1[j] = cvt_bf16(a[8 + j]); }
      *(bf16x8*)&As[r * 64 + ((ca       ^ (r & 7)) * 8)] = v0;
      *(bf16x8*)&As[r * 64 + (((ca + 1) ^ (r & 7)) * 8)] = v1;
      int n = tid & 63, cb = (tid >> 6) * 2;
      bf16x8 w0, w1;
      #pragma unroll
      for (int j = 0; j < 8; ++j) { w0[j] = cvt_bf16(bw[j]); w1[j] = cvt_bf16(bw[8 + j]); }
      *(bf16x8*)&Bs[n * 64 + ((cb       ^ (n & 7)) * 8)] = w0;
      *(bf16x8*)&Bs[n * 64 + (((cb + 1) ^ (n & 7)) * 8)] = w1;
    };

    const int lane = tid & 63, wave = tid >> 6;
    const int quad = lane >> 4, l15 = lane & 15;
    const int wm = wave >> 1, wn = wave & 1;
    floatx4 acc[2][2] = {};

    loadA(0); loadB(0);
    for (int k0 = 0; k0 < DM; k0 += 64) {
      store();
      __syncthreads();
      if (k0 + 64 < DM) { loadA(k0 + 64); loadB(k0 + 64); }
      #pragma unroll
      for (int kk = 0; kk < 2; ++kk) {
        bf16x8 af[2], bfr[2];
        #pragma unroll
        for (int mt = 0; mt < 2; ++mt) {
          int r = wm * 32 + mt * 16 + l15;
          af[mt] = *(const bf16x8*)&As[r * 64 + (((kk * 4 + quad) ^ (r & 7)) * 8)];
        }
        #pragma unroll
        for (int nt = 0; nt < 2; ++nt) {
          int r = wn * 32 + nt * 16 + l15;
          bfr[nt] = *(const bf16x8*)&Bs[r * 64 + (((kk * 4 + quad) ^ (r & 7)) * 8)];
        }
        #pragma unroll
        for (int mt = 0; mt < 2; ++mt)
          #pragma unroll
          for (int nt = 0; nt < 2; ++nt)
            acc[mt][nt] = __builtin_amdgcn_mfma_f32_16x16x32_bf16(af[mt], bfr[nt], acc[mt][nt], 0, 0, 0);
      }
      __syncthreads();
    }

    #pragma unroll
    for (int mt = 0; mt < 2; ++mt)
      #pragma unroll
      for (int nt = 0; nt < 2; ++nt) {
        int cl = wn * 32 + nt * 16 + l15;
        #pragma unroll
        for (int r = 0; r < 4; ++r) {
          int row = m0 + wm * 32 + mt * 16 + quad * 4 + r;
          float v = acc[mt][nt][r] + bias[nc0 + cl];
          if (n0 < 128) Kb[(size_t)row * DH + nc0 + cl]      = cvt_bf16(v);
          else          Vt[(size_t)(nc0 + cl) * NSEQ + row]  = cvt_bf16(v);
        }
      }
    return;
  }
  id -= 128;

  if (id < 8192) {                       // ---- cast x ----
    int i = (id * 256 + tid) * 4;
    float4 v = *(const float4*)&x[i];
    bf16x4 o;
    o[0] = cvt_bf16(v.x); o[1] = cvt_bf16(v.y);
    o[2] = cvt_bf16(v.z); o[3] = cvt_bf16(v.w);
    *(bf16x4*)&xb[i] = o;
    return;
  }
  id -= 8192;

  // ---- transpose Wq (ids < 4096) or Wo (ids >= 4096) : 64x64 tile ----
  const float* in; bf16* out;
  if (id < 4096) { in = Wq; out = WqT; }
  else           { id -= 4096; in = Wo; out = WoT; }
  bf16 (*t)[72] = (bf16(*)[72])&smem[0];
  int bx = id & 63, by = id >> 6;
  int tx = tid & 15, ty = tid >> 4;
  int r0 = by * 64, c0 = bx * 64;
  #pragma unroll
  for (int i = 0; i < 4; ++i) {
    float4 v = *(const float4*)&in[(size_t)(r0 + ty + i * 16) * DM + c0 + tx * 4];
    bf16x4 b;
    b[0] = cvt_bf16(v.x); b[1] = cvt_bf16(v.y);
    b[2] = cvt_bf16(v.z); b[3] = cvt_bf16(v.w);
    *(bf16x4*)&t[ty + i * 16][tx * 4] = b;
  }
  __syncthreads();
  #pragma unroll
  for (int i = 0; i < 4; ++i) {
    int cc = ty + i * 16;
    bf16x4 o;
    #pragma unroll
    for (int j = 0; j < 4; ++j) o[j] = t[tx * 4 + j][cc];
    *(bf16x4*)&out[(size_t)(c0 + cc) * DM + r0 + tx * 4] = o;
  }
}

// ---------- standalone Wo transpose (small-ws fallback only) ----------

__global__ void wo_t(const float* __restrict__ in, bf16* __restrict__ out) {
  __shared__ bf16 t[64][72];
  int tx = threadIdx.x & 15, ty = threadIdx.x >> 4;
  int r0 = blockIdx.y * 64, c0 = blockIdx.x * 64;
  #pragma unroll
  for (int i = 0; i < 4; ++i) {
    float4 v = *(const float4*)&in[(size_t)(r0 + ty + i * 16) * DM + c0 + tx * 4];
    bf16x4 b;
    b[0] = cvt_bf16(v.x); b[1] = cvt_bf16(v.y);
    b[2] = cvt_bf16(v.z); b[3] = cvt_bf16(v.w);
    *(bf16x4*)&t[ty + i * 16][tx * 4] = b;
  }
  __syncthreads();
  #pragma unroll
  for (int i = 0; i < 4; ++i) {
    int cc = ty + i * 16;
    bf16x4 o;
    #pragma unroll
    for (int j = 0; j < 4; ++j) o[j] = t[tx * 4 + j][cc];
    *(bf16x4*)&out[(size_t)(c0 + cc) * DM + r0 + tx * 4] = o;
  }
}

// ---------- NT GEMM core: C[M,N] = A[M,K] * B[N,K]^T + bias ----------
// m97 recipe, 16x16x32 MFMA, single-barrier double-buffered gload_lds staging.
// MODE 0: f32 out + bias (global)
// MODE 2: bf16 out to LDS tile outb[128][128], (v+bias[col])*QSCALE

template<int BM, int BN, int MODE>
__device__ __forceinline__ void gemm_core(
    const bf16* __restrict__ A, const bf16* __restrict__ B,
    const float* __restrict__ bias,
    float* __restrict__ outf, bf16* __restrict__ outb,
    int N, int K, int m0, int n0,
    bf16* __restrict__ As, bf16* __restrict__ Bs)
{
  constexpr int BK = 64;
  constexpr int TM = BM / 2, TN = BN / 2;
  constexpr int MT = TM / 16, NT = TN / 16;
  const int tid  = threadIdx.x;
  const int lane = tid & 63;
  const int wave = tid >> 6;
  const int quad = lane >> 4;
  const int l15  = lane & 15;
  const int wm = wave >> 1, wn = wave & 1;

  auto stage = [&](int k0, int buf) {
    #pragma unroll
    for (int i = 0; i < BM / 32; ++i) {
      int c = i * 256 + tid;
      int r = c >> 3, kc = (c & 7) ^ (r & 7);          // 8-chunk XOR swizzle
      gload_lds16(A + (size_t)(m0 + r) * K + k0 + kc * 8, &As[buf * BM * BK + c * 8]);
    }
    #pragma unroll
    for (int i = 0; i < BN / 32; ++i) {
      int c = i * 256 + tid;
      int r = c >> 3, kc = (c & 7) ^ (r & 7);
      gload_lds16(B + (size_t)(n0 + r) * K + k0 + kc * 8, &Bs[buf * BN * BK + c * 8]);
    }
  };

  floatx4 acc[MT][NT] = {};
  stage(0, 0);

  int b = 0;
  for (int k0 = 0; k0 < K; k0 += BK, b ^= 1) {
    __syncthreads();                                    // drains staging of buf b
    if (k0 + BK < K) stage(k0 + BK, b ^ 1);             // overlaps compute below

    #pragma unroll
    for (int kk = 0; kk < 2; ++kk) {
      bf16x8 af[MT], bfr[NT];
      #pragma unroll
      for (int mt = 0; mt < MT; ++mt) {
        int r = wm * TM + mt * 16 + l15;
        af[mt] = *(const bf16x8*)&As[b * BM * BK + r * BK + (((kk * 4 + quad) ^ (r & 7)) * 8)];
      }
      #pragma unroll
      for (int nt = 0; nt < NT; ++nt) {
        int r = wn * TN + nt * 16 + l15;
        bfr[nt] = *(const bf16x8*)&Bs[b * BN * BK + r * BK + (((kk * 4 + quad) ^ (r & 7)) * 8)];
      }
      #pragma unroll
      for (int mt = 0; mt < MT; ++mt)
        #pragma unroll
        for (int nt = 0; nt < NT; ++nt)
          acc[mt][nt] = __builtin_amdgcn_mfma_f32_16x16x32_bf16(af[mt], bfr[nt], acc[mt][nt], 0, 0, 0);
    }
  }

  if constexpr (MODE == 2) __syncthreads();             // outb aliases As

  #pragma unroll
  for (int mt = 0; mt < MT; ++mt) {
    #pragma unroll
    for (int nt = 0; nt < NT; ++nt) {
      int col = n0 + wn * TN + nt * 16 + l15;
      #pragma unroll
      for (int r = 0; r < 4; ++r) {
        int row = m0 + wm * TM + mt * 16 + quad * 4 + r;
        float v = acc[mt][nt][r];
        if constexpr (MODE == 0) {
          outf[(size_t)row * N + col] = v + bias[col];
        } else {  // MODE 2: LDS Q tile
          int rl = wm * TM + mt * 16 + quad * 4 + r;
          int cl = wn * TN + nt * 16 + l15;
          outb[rl * 128 + cl] = cvt_bf16((v + bias[col]) * QSCALE);
        }
      }
    }
  }
}

// ---------- O projection (512 blocks = exactly 2/CU capacity) ----------

__global__ __launch_bounds__(256)
void o_gemm(const bf16* __restrict__ Ob, const bf16* __restrict__ WoT,
            const float* __restrict__ bo, float* __restrict__ out)
{
  __shared__ __align__(16) bf16 As[2 * 128 * 64];
  __shared__ __align__(16) bf16 Bs[2 * 128 * 64];
  int id = blockIdx.x;
  const int per = 4 * (DM / 128);
  int m0 = ((id / per) * 4 + (id % per) % 4) * 128;
  int n0 = ((id % per) / 4) * 128;
  gemm_core<128, 128, 0>(Ob, WoT, bo, out, nullptr, DM, DM, m0, n0, As, Bs);
}

// ---------- fused Q-GEMM + flash MQA attention (R5-verified) ----------
// Each block (qb,h) computes ITS OWN 128x128 Q tile (m97 GEMM, K=4096) into
// LDS, re-reads it as MFMA B-fragments, then runs flash attention. No Qb HBM
// round-trip; gemm->attn transition is per-block (blocks de-phase naturally).
// LDS: union{gemm 64KB, attn 80KB} = 80KB -> 2 blocks/CU (grid 512 = 2/CU).
// R7 lesson: do NOT chain the O-projection in-kernel — per-block agent-scope
// release/acquire fences invalidate the XCD L2 512x (~+100us). Kernel
// boundary = one global wb/inv, strictly cheaper.

struct GemmSm { bf16 As[2 * 128 * 64]; bf16 Bs[2 * 128 * 64]; };
struct AttnSm { bf16 Ks[2][64 * DH]; bf16 Vs[2][DH * 64]; bf16 Pl[4][32 * 64]; };
union FlashSm { GemmSm g; AttnSm a; bf16 Qt[128 * 128]; };

__global__ __launch_bounds__(256)
void flash_q(const bf16* __restrict__ xb, const bf16* __restrict__ WqT,
             const float* __restrict__ bq,
             const bf16* __restrict__ Kb, const bf16* __restrict__ Vt,
             bf16* __restrict__ Ob)
{
  constexpr int KT = 64;
  __shared__ __align__(16) FlashSm sm;
  const int tid = threadIdx.x, lane = tid & 63, wave = tid >> 6;
  const int quad = lane >> 4, l15 = lane & 15;

  const int id  = blockIdx.x;
  const int per = 4 * (DM / 128);                 // 128 (group-of-4 m swizzle)
  const int qb  = (id / per) * 4 + (id % per) % 4;
  const int h   = (id % per) / 4;

  // ---- phase 1: Q tile = xb[qb*128..][:] @ WqT[h*128..][:]^T ----
  gemm_core<128, 128, 2>(xb, WqT, bq, nullptr, sm.Qt, DM, DM,
                         qb * 128, h * 128, sm.g.As, sm.g.Bs);
  __syncthreads();                                // Qt complete

  bf16x8 qf[2][4];
  #pragma unroll
  for (int mt = 0; mt < 2; ++mt)
    #pragma unroll
    for (int kf = 0; kf < 4; ++kf)
      qf[mt][kf] = *(const bf16x8*)&sm.Qt[(wave * 32 + mt * 16 + l15) * 128 + kf * 32 + quad * 8];
  __syncthreads();                                // qf read before Ks overwrites Qt

  // ---- phase 2: flash attention ----
  const int q0 = qb * 128 + wave * 32;

  auto stage = [&](int kt, int buf) {
    #pragma unroll
    for (int i = 0; i < 4; ++i) {                  // K tile (64 x 128)
      int c = i * 256 + tid, n = c >> 4, kc = (c & 15) ^ (n & 15);
      gload_lds16(Kb + (size_t)(kt + n) * DH + kc * 8, &sm.a.Ks[buf][c * 8]);
    }
    #pragma unroll
    for (int i = 0; i < 4; ++i) {                  // V tile (128 x 64)
      int c = i * 256 + tid, n = c >> 3, kc = (c & 7) ^ (n & 7);
      gload_lds16(Vt + (size_t)n * NSEQ + kt + kc * 8, &sm.a.Vs[buf][c * 8]);
    }
  };

  floatx4 o[2][8] = {};
  float lsum[2] = {0.f, 0.f};
  stage(0, 0);

  int b = 0;
  for (int kt = 0; kt < NSEQ; kt += KT, b ^= 1) {
    __syncthreads();                               // drains staging of buf b
    if (kt + KT < NSEQ) stage(kt + KT, b ^ 1);     // overlaps compute below

    // St = K Q^T
    #pragma unroll
    for (int nt = 0; nt < 4; ++nt) {
      bf16x8 kfr[4];
      #pragma unroll
      for (int kf = 0; kf < 4; ++kf) {
        int r = nt * 16 + l15;
        kfr[kf] = *(const bf16x8*)&sm.a.Ks[b][r * DH + (((kf * 4 + quad) ^ (r & 15)) * 8)];
      }
      floatx4 s[2] = {};
      __builtin_amdgcn_s_setprio(1);
      #pragma unroll
      for (int kf = 0; kf < 4; ++kf)
        #pragma unroll
        for (int mt = 0; mt < 2; ++mt)
          s[mt] = __builtin_amdgcn_mfma_f32_16x16x32_bf16(kfr[kf], qf[mt][kf], s[mt], 0, 0, 0);
      __builtin_amdgcn_s_setprio(0);
      // p = exp2(s); in-lane l accumulation; packed b64 P write
      #pragma unroll
      for (int mt = 0; mt < 2; ++mt) {
        float p0 = __builtin_amdgcn_exp2f(s[mt][0]);
        float p1 = __builtin_amdgcn_exp2f(s[mt][1]);
        float p2 = __builtin_amdgcn_exp2f(s[mt][2]);
        float p3 = __builtin_amdgcn_exp2f(s[mt][3]);
        lsum[mt] += (p0 + p1) + (p2 + p3);
        uint2 pk;
        pk.x = pack_bf16_2(p0, p1);
        pk.y = pack_bf16_2(p2, p3);
        int row = mt * 16 + l15;
        int cp  = (nt * 2 + (quad >> 1)) ^ (row & 7);      // 8-chunk XOR swizzle
        *(uint2*)&sm.a.Pl[wave][row * KT + cp * 8 + (quad & 1) * 4] = pk;
      }
    }

    // O += P V
    #pragma unroll
    for (int kf = 0; kf < 2; ++kf) {
      bf16x8 pf[2];
      #pragma unroll
      for (int mt = 0; mt < 2; ++mt) {
        int row = mt * 16 + l15;
        pf[mt] = *(const bf16x8*)&sm.a.Pl[wave][row * KT + (((kf * 4 + quad) ^ (row & 7)) * 8)];
      }
      __builtin_amdgcn_s_setprio(1);
      #pragma unroll
      for (int dt = 0; dt < 8; ++dt) {
        int r = dt * 16 + l15;
        bf16x8 vf = *(const bf16x8*)&sm.a.Vs[b][r * KT + (((kf * 4 + quad) ^ (r & 7)) * 8)];
        #pragma unroll
        for (int mt = 0; mt < 2; ++mt)
          o[mt][dt] = __builtin_amdgcn_mfma_f32_16x16x32_bf16(pf[mt], vf, o[mt][dt], 0, 0, 0);
      }
      __builtin_amdgcn_s_setprio(0);
    }
  }

  // final l reduction across quads, then Ob epilogue
  #pragma unroll
  for (int mt = 0; mt < 2; ++mt) {
    lsum[mt] += __shfl_xor(lsum[mt], 16, 64);
    lsum[mt] += __shfl_xor(lsum[mt], 32, 64);
  }

  #pragma unroll
  for (int mt = 0; mt < 2; ++mt) {
    float inv[4];
    #pragma unroll
    for (int r = 0; r < 4; ++r)
      inv[r] = 1.0f / __shfl(lsum[mt], quad * 4 + r, 64);
    #pragma unroll
    for (int dt = 0; dt < 8; ++dt) {
      int col = h * DH + dt * 16 + l15;
      #pragma unroll
      for (int r = 0; r < 4; ++r) {
        int row = q0 + mt * 16 + quad * 4 + r;
        Ob[(size_t)row * DM + col] = cvt_bf16(o[mt][dt][r] * inv[r]);
      }
    }
  }
}

// ---------- launch ----------

extern "C" void kernel_launch(void* const* d_in, const int* in_sizes, int n_in,
                              void* d_out, int out_size, void* d_ws, size_t ws_size,
                              hipStream_t stream) {
  (void)in_sizes; (void)n_in; (void)out_size;
  const float* x  = (const float*)d_in[0];
  const float* Wq = (const float*)d_in[1];
  const float* bq = (const float*)d_in[2];
  const float* Wk = (const float*)d_in[3];
  const float* bk = (const float*)d_in[4];
  const float* Wv = (const float*)d_in[5];
  const float* bv = (const float*)d_in[6];
  const float* Wo = (const float*)d_in[7];
  const float* bo = (const float*)d_in[8];
  float* out = (float*)d_out;

  char* ws = (char*)d_ws;
  size_t off = 0;
  auto alloc = [&](size_t bytes) {
    char* p = ws + off;
    off += (bytes + 255) & ~(size_t)255;
    return p;
  };
  bf16*  xb  = (bf16*)alloc((size_t)NSEQ * DM * 2);   // x bf16
  bf16*  WT  = (bf16*)alloc((size_t)DM * DM * 2);     // WqT (and WoT in fallback)
  bf16*  Ob  = (bf16*)alloc((size_t)NSEQ * DM * 2);   // attention output
  bf16*  Kb  = (bf16*)alloc((size_t)NSEQ * DH * 2);
  bf16*  Vt  = (bf16*)alloc((size_t)DH * NSEQ * 2);
  size_t base_off = off;
  bf16* WoTbuf = (bf16*)alloc((size_t)DM * DM * 2);   // dedicated WoT (big-ws path)
  if (base_off > ws_size) return;                     // cannot run at all
  const bool bigws = (off <= ws_size);
  bf16* WoT = bigws ? WoTbuf : WT;

  // 1) prep: KV projection + x cast + Wq transpose (+ Wo transpose if bigws)
  prep_all<<<bigws ? 16512 : 12416, 256, 0, stream>>>(
      x, Wq, Wk, Wv, bk, bv, xb, WT, Kb, Vt, Wo, bigws ? WoTbuf : nullptr);

  // 2) fused Q-projection + attention (512 blocks = exactly 2/CU)
  flash_q<<<512, 256, 0, stream>>>(xb, WT, bq, Kb, Vt, Ob);

  // 3) Wo transpose only needed as separate launch when ws is small
  if (!bigws)
    wo_t<<<dim3(DM / 64, DM / 64), 256, 0, stream>>>(Wo, WT);

  // 4) output projection (512 blocks = exactly 2/CU capacity)
  o_gemm<<<512, 256, 0, stream>>>(Ob, WoT, bo, out);
}